// Round 5
// baseline (127.033 us; speedup 1.0000x reference)
//
#include <hip/hip_runtime.h>

// SplineActivation: out[b,d] = sum_k basis_k(x[b,d]) * coeffs[d,k]
// Uniform cubic B-spline. Each thread owns 4 fixed d-columns; per column the
// 4 cells' cubic polynomial coeffs (in local coord s) are precomputed into
// registers. Per element: cell select via cndmask + 3-FMA Horner.
// No LDS, no barrier. Streaming float4 in/out.

#define D     4096
#define B     4096
#define NB    7
#define DTILE 1024
#define ROWS  8

constexpr int NDT = D / DTILE;   // 4 d-tiles
constexpr int NRT = B / ROWS;    // 512 row-tiles -> grid 2048

__global__ __launch_bounds__(256, 4) void
spline_act_kernel(const float* __restrict__ x,
                  const float* __restrict__ coeffs,
                  float* __restrict__ out) {
    const int bid   = blockIdx.x;
    const int dt    = bid & (NDT - 1);
    const int rowt  = bid >> 2;
    const int dbase = dt * DTILE;
    const int tid   = threadIdx.x;

    const int d0 = dbase + 4 * tid;   // first of this thread's 4 d-columns

    // Per-cell cubic poly coeffs in s: p(s) = q0 + s(q1 + s(q2 + s*q3)).
    // [col][cell], 64 floats, held in registers for the whole kernel.
    float pa0[4][4], pa1[4][4], pa2[4][4], pa3[4][4];
#pragma unroll
    for (int col = 0; col < 4; ++col) {
        const float* cr = coeffs + (size_t)(d0 + col) * NB;
        float tap[NB];
#pragma unroll
        for (int k = 0; k < NB; ++k) tap[k] = cr[k];
#pragma unroll
        for (int c = 0; c < 4; ++c) {
            float cA = tap[c], cB = tap[c + 1], cC = tap[c + 2], cD = tap[c + 3];
            pa0[col][c] = (cA + 4.0f * cB + cC) * (1.0f / 6.0f);
            pa1[col][c] = (cC - cA) * 0.5f;
            pa2[col][c] = (cA - 2.0f * cB + cC) * 0.5f;
            pa3[col][c] = ((cD - cA) + 3.0f * (cB - cC)) * (1.0f / 6.0f);
        }
    }

    const float4* x4 = reinterpret_cast<const float4*>(x);
    float4*       o4 = reinterpret_cast<float4*>(out);
    const int colbase = (dbase >> 2) + tid;
    const int rowbase = rowt * ROWS;

#pragma unroll
    for (int g = 0; g < ROWS / 4; ++g) {
        float4 xv[4];
        int    idx[4];
#pragma unroll
        for (int it = 0; it < 4; ++it) {   // 4 loads in flight
            idx[it] = (rowbase + g * 4 + it) * (D / 4) + colbase;
            xv[it]  = x4[idx[it]];
        }
#pragma unroll
        for (int it = 0; it < 4; ++it) {
            float xs[4] = {xv[it].x, xv[it].y, xv[it].z, xv[it].w};
            float r[4];
#pragma unroll
            for (int j = 0; j < 4; ++j) {
                float u = fmaf(xs[j], 2.0f, 2.0f);   // cell coord in [0,4]
                int c = (int)u;                       // trunc == floor (u >= 0)
                c = c > 3 ? 3 : c;                    // x == 1.0 edge
                float s = u - (float)c;

                bool hi = c >= 2;
                bool lo = (c & 1) != 0;
                float q0 = hi ? (lo ? pa0[j][3] : pa0[j][2]) : (lo ? pa0[j][1] : pa0[j][0]);
                float q1 = hi ? (lo ? pa1[j][3] : pa1[j][2]) : (lo ? pa1[j][1] : pa1[j][0]);
                float q2 = hi ? (lo ? pa2[j][3] : pa2[j][2]) : (lo ? pa2[j][1] : pa2[j][0]);
                float q3 = hi ? (lo ? pa3[j][3] : pa3[j][2]) : (lo ? pa3[j][1] : pa3[j][0]);

                r[j] = fmaf(s, fmaf(s, fmaf(s, q3, q2), q1), q0);
            }
            o4[idx[it]] = make_float4(r[0], r[1], r[2], r[3]);
        }
    }
}

extern "C" void kernel_launch(void* const* d_in, const int* in_sizes, int n_in,
                              void* d_out, int out_size, void* d_ws, size_t ws_size,
                              hipStream_t stream) {
    const float* x      = (const float*)d_in[0];   // (4096, 4096) fp32
    const float* coeffs = (const float*)d_in[1];   // (4096, 7) fp32
    float* out          = (float*)d_out;           // (4096, 4096) fp32

    const int grid = NDT * NRT;   // 2048 blocks x 256 threads
    spline_act_kernel<<<grid, 256, 0, stream>>>(x, coeffs, out);
}